// Round 1
// baseline (733.373 us; speedup 1.0000x reference)
//
#include <hip/hip_runtime.h>

#define F 128
#define CLSN 40

// ---------------- CSR build ----------------
__global__ void k_deg(const int* __restrict__ dst, int* __restrict__ deg, int E) {
  int e = blockIdx.x * blockDim.x + threadIdx.x;
  if (e < E) atomicAdd(&deg[dst[e]], 1);
}

// single-block sequential chunked scan over n elements (n ~ 100k)
__global__ void k_scan(const int* __restrict__ deg, int* __restrict__ offsets, int n) {
  __shared__ int s_carry;
  __shared__ int s_wsum[16];
  const int tid = threadIdx.x, lane = tid & 63, w = tid >> 6;
  if (tid == 0) s_carry = 0;
  __syncthreads();
  for (int base = 0; base < n; base += 1024) {
    int i = base + tid;
    int v = (i < n) ? deg[i] : 0;
    int s = v;
#pragma unroll
    for (int d = 1; d < 64; d <<= 1) {
      int t = __shfl_up(s, d);
      if (lane >= d) s += t;
    }
    if (lane == 63) s_wsum[w] = s;
    __syncthreads();
    if (w == 0) {
      int ws = (lane < 16) ? s_wsum[lane] : 0;
#pragma unroll
      for (int d = 1; d < 16; d <<= 1) {
        int t = __shfl_up(ws, d);
        if (lane >= d) ws += t;
      }
      if (lane < 16) s_wsum[lane] = ws;
    }
    __syncthreads();
    int add = s_carry + ((w > 0) ? s_wsum[w - 1] : 0);
    int incl = s + add;
    if (i < n) offsets[i + 1] = incl;
    __syncthreads();
    if (tid == 1023) s_carry = incl;
    __syncthreads();
  }
  if (tid == 0) offsets[0] = 0;
}

__global__ void k_copy(const int* __restrict__ offsets, int* __restrict__ cursor, int n) {
  int i = blockIdx.x * blockDim.x + threadIdx.x;
  if (i < n) cursor[i] = offsets[i];
}

__global__ void k_scatter(const int* __restrict__ src, const int* __restrict__ dst,
                          int* __restrict__ cursor, int* __restrict__ srcs, int E) {
  int e = blockIdx.x * blockDim.x + threadIdx.x;
  if (e < E) {
    int d = dst[e];
    int p = atomicAdd(&cursor[d], 1);
    srcs[p] = src[e];
  }
}

// ---------------- mean aggregation: one wave per node ----------------
__global__ __launch_bounds__(256) void k_aggregate(const float* __restrict__ feat,
                                                   const int* __restrict__ offsets,
                                                   const int* __restrict__ srcs,
                                                   float* __restrict__ mean, int n) {
  int gw = (blockIdx.x * 256 + threadIdx.x) >> 6;
  int lane = threadIdx.x & 63;
  if (gw >= n) return;
  int beg = offsets[gw], end = offsets[gw + 1];
  float ax = 0.f, ay = 0.f;
  for (int chunk = beg; chunk < end; chunk += 64) {
    int cnt = min(64, end - chunk);
    int s = (lane < cnt) ? srcs[chunk + lane] : 0;
    int k = 0;
    for (; k + 3 < cnt; k += 4) {
      int s0 = __shfl(s, k), s1 = __shfl(s, k + 1);
      int s2 = __shfl(s, k + 2), s3 = __shfl(s, k + 3);
      float2 v0 = *reinterpret_cast<const float2*>(feat + (size_t)s0 * F + lane * 2);
      float2 v1 = *reinterpret_cast<const float2*>(feat + (size_t)s1 * F + lane * 2);
      float2 v2 = *reinterpret_cast<const float2*>(feat + (size_t)s2 * F + lane * 2);
      float2 v3 = *reinterpret_cast<const float2*>(feat + (size_t)s3 * F + lane * 2);
      ax += v0.x + v1.x + v2.x + v3.x;
      ay += v0.y + v1.y + v2.y + v3.y;
    }
    for (; k < cnt; ++k) {
      int s0 = __shfl(s, k);
      float2 v0 = *reinterpret_cast<const float2*>(feat + (size_t)s0 * F + lane * 2);
      ax += v0.x;
      ay += v0.y;
    }
  }
  int dg = end - beg;
  float inv = dg > 0 ? 1.f / (float)dg : 0.f;
  *reinterpret_cast<float2*>(mean + (size_t)gw * F + lane * 2) = make_float2(ax * inv, ay * inv);
}

// ---------------- layer1 GEMM: h = relu(mean@Wl + x@Wr + b) ----------------
__global__ __launch_bounds__(256) void k_gemm1(const float* __restrict__ mean,
                                               const float* __restrict__ x,
                                               const float* __restrict__ Wl,
                                               const float* __restrict__ Wr,
                                               const float* __restrict__ b,
                                               float* __restrict__ h, int nrows) {
  __shared__ float lds[64 * 256];  // [row][2*k + {mean,x}]
  const int tid = threadIdx.x;
  const int row0 = blockIdx.x * 64;
#pragma unroll
  for (int i = 0; i < 8; ++i) {
    int slot = tid + i * 256;  // 2048 float4 slots
    int r = slot >> 5;
    int kq = slot & 31;
    int grow = row0 + r;
    float4 m4 = make_float4(0.f, 0.f, 0.f, 0.f), x4 = make_float4(0.f, 0.f, 0.f, 0.f);
    if (grow < nrows) {
      m4 = *reinterpret_cast<const float4*>(mean + (size_t)grow * F + kq * 4);
      x4 = *reinterpret_cast<const float4*>(x + (size_t)grow * F + kq * 4);
    }
    float* p = &lds[r * 256 + kq * 8];
    reinterpret_cast<float2*>(p)[0] = make_float2(m4.x, x4.x);
    reinterpret_cast<float2*>(p)[1] = make_float2(m4.y, x4.y);
    reinterpret_cast<float2*>(p)[2] = make_float2(m4.z, x4.z);
    reinterpret_cast<float2*>(p)[3] = make_float2(m4.w, x4.w);
  }
  __syncthreads();
  const int lane = tid & 63;
  const int wv = tid >> 6;
  const int rbase = wv * 16;
  const int c0 = lane * 2;
  float2 acc[16];
#pragma unroll
  for (int r = 0; r < 16; ++r) acc[r] = make_float2(0.f, 0.f);
#pragma unroll 2
  for (int k = 0; k < F; k += 2) {
    float2 wl0 = *reinterpret_cast<const float2*>(Wl + k * F + c0);
    float2 wl1 = *reinterpret_cast<const float2*>(Wl + (k + 1) * F + c0);
    float2 wr0 = *reinterpret_cast<const float2*>(Wr + k * F + c0);
    float2 wr1 = *reinterpret_cast<const float2*>(Wr + (k + 1) * F + c0);
#pragma unroll
    for (int r = 0; r < 16; ++r) {
      float4 mx = *reinterpret_cast<const float4*>(&lds[(rbase + r) * 256 + k * 2]);
      acc[r].x += mx.x * wl0.x + mx.y * wr0.x + mx.z * wl1.x + mx.w * wr1.x;
      acc[r].y += mx.x * wl0.y + mx.y * wr0.y + mx.z * wl1.y + mx.w * wr1.y;
    }
  }
  float2 bias = *reinterpret_cast<const float2*>(b + c0);
#pragma unroll
  for (int r = 0; r < 16; ++r) {
    int grow = row0 + rbase + r;
    if (grow < nrows) {
      float2 o;
      o.x = fmaxf(acc[r].x + bias.x, 0.f);
      o.y = fmaxf(acc[r].y + bias.y, 0.f);
      *reinterpret_cast<float2*>(h + (size_t)grow * F + c0) = o;
    }
  }
}

// ---------------- layer2 GEMM: out = mean2@Wl2 + h@Wr2 + b2 ----------------
__global__ __launch_bounds__(256) void k_gemm2(const float* __restrict__ mean2,
                                               const float* __restrict__ h,
                                               const float* __restrict__ Wl,
                                               const float* __restrict__ Wr,
                                               const float* __restrict__ b,
                                               float* __restrict__ out, int nrows) {
  __shared__ float lds[64 * 256];  // [row][2*k + {mean2,h}]
  const int tid = threadIdx.x;
  const int row0 = blockIdx.x * 64;
#pragma unroll
  for (int i = 0; i < 8; ++i) {
    int slot = tid + i * 256;
    int r = slot >> 5;
    int kq = slot & 31;
    int grow = row0 + r;
    float4 m4 = make_float4(0.f, 0.f, 0.f, 0.f), h4 = make_float4(0.f, 0.f, 0.f, 0.f);
    if (grow < nrows) {
      m4 = *reinterpret_cast<const float4*>(mean2 + (size_t)grow * F + kq * 4);
      h4 = *reinterpret_cast<const float4*>(h + (size_t)grow * F + kq * 4);
    }
    float* p = &lds[r * 256 + kq * 8];
    reinterpret_cast<float2*>(p)[0] = make_float2(m4.x, h4.x);
    reinterpret_cast<float2*>(p)[1] = make_float2(m4.y, h4.y);
    reinterpret_cast<float2*>(p)[2] = make_float2(m4.z, h4.z);
    reinterpret_cast<float2*>(p)[3] = make_float2(m4.w, h4.w);
  }
  __syncthreads();
  const int lane = tid & 63;
  const int wv = tid >> 6;
  const int rbase = wv * 16;
  const int cc = (lane < CLSN) ? lane : (CLSN - 1);  // clamp to stay in bounds
  float acc[16];
#pragma unroll
  for (int r = 0; r < 16; ++r) acc[r] = 0.f;
#pragma unroll 2
  for (int k = 0; k < F; k += 2) {
    float wl0 = Wl[k * CLSN + cc], wl1 = Wl[(k + 1) * CLSN + cc];
    float wr0 = Wr[k * CLSN + cc], wr1 = Wr[(k + 1) * CLSN + cc];
#pragma unroll
    for (int r = 0; r < 16; ++r) {
      float4 mx = *reinterpret_cast<const float4*>(&lds[(rbase + r) * 256 + k * 2]);
      acc[r] += mx.x * wl0 + mx.y * wr0 + mx.z * wl1 + mx.w * wr1;
    }
  }
  if (lane < CLSN) {
    float bb = b[lane];
#pragma unroll
    for (int r = 0; r < 16; ++r) {
      int grow = row0 + rbase + r;
      if (grow < nrows) out[(size_t)grow * CLSN + lane] = acc[r] + bb;
    }
  }
}

extern "C" void kernel_launch(void* const* d_in, const int* in_sizes, int n_in,
                              void* d_out, int out_size, void* d_ws, size_t ws_size,
                              hipStream_t stream) {
  const float* x = (const float*)d_in[0];
  const int* ei = (const int*)d_in[1];
  const float* Wl1 = (const float*)d_in[2];
  const float* Wr1 = (const float*)d_in[3];
  const float* b1 = (const float*)d_in[4];
  const float* Wl2 = (const float*)d_in[5];
  const float* Wr2 = (const float*)d_in[6];
  const float* b2 = (const float*)d_in[7];
  float* out = (float*)d_out;

  const int n = in_sizes[0] / F;
  const int E = in_sizes[1] / 2;
  const int* src = ei;
  const int* dst = ei + E;

  // workspace layout (256B aligned regions)
  size_t off = 0;
  auto alloc = [&](size_t bytes) {
    size_t cur = off;
    off = (off + bytes + 255) & ~(size_t)255;
    return cur;
  };
  char* w = (char*)d_ws;
  int* deg = (int*)(w + alloc((size_t)n * 4));
  int* offsets = (int*)(w + alloc((size_t)(n + 1) * 4));
  int* cursor = (int*)(w + alloc((size_t)n * 4));
  int* srcs = (int*)(w + alloc((size_t)E * 4));
  float* mean = (float*)(w + alloc((size_t)n * F * 4));
  float* hbuf = (float*)(w + alloc((size_t)n * F * 4));
  (void)ws_size;

  hipMemsetAsync(deg, 0, (size_t)n * 4, stream);
  k_deg<<<(E + 255) / 256, 256, 0, stream>>>(dst, deg, E);
  k_scan<<<1, 1024, 0, stream>>>(deg, offsets, n);
  k_copy<<<(n + 255) / 256, 256, 0, stream>>>(offsets, cursor, n);
  k_scatter<<<(E + 255) / 256, 256, 0, stream>>>(src, dst, cursor, srcs, E);

  // layer 1: mean-aggregate x, then h = relu(mean@Wl1 + x@Wr1 + b1)
  k_aggregate<<<(n * 64 + 255) / 256, 256, 0, stream>>>(x, offsets, srcs, mean, n);
  k_gemm1<<<(n + 63) / 64, 256, 0, stream>>>(mean, x, Wl1, Wr1, b1, hbuf, n);

  // layer 2: mean-aggregate h, then out = mean2@Wl2 + h@Wr2 + b2
  k_aggregate<<<(n * 64 + 255) / 256, 256, 0, stream>>>(hbuf, offsets, srcs, mean, n);
  k_gemm2<<<(n + 63) / 64, 256, 0, stream>>>(mean, hbuf, Wl2, Wr2, b2, out, n);
}

// Round 2
// 381.016 us; speedup vs baseline: 1.9248x; 1.9248x over previous
//
#include <hip/hip_runtime.h>

#define F 128
#define CLSN 40

typedef __attribute__((ext_vector_type(8))) short short8v;
typedef __attribute__((ext_vector_type(4))) float float4v;

static __device__ inline ushort f2bf(float f) {
  uint u = __float_as_uint(f);
  uint r = (u + 0x7FFFu + ((u >> 16) & 1u)) >> 16;
  return (ushort)r;
}

// ---------------- casts / packing ----------------
__global__ __launch_bounds__(256) void k_cast(const float* __restrict__ in,
                                              ushort* __restrict__ outb, int nelem4) {
  int i = blockIdx.x * 256 + threadIdx.x;
  if (i < nelem4) {
    float4 v = reinterpret_cast<const float4*>(in)[i];
    ushort4 o;
    o.x = f2bf(v.x); o.y = f2bf(v.y); o.z = f2bf(v.z); o.w = f2bf(v.w);
    reinterpret_cast<ushort4*>(outb)[i] = o;
  }
}

// pack [Wl;Wr] (256x128 f32) into MFMA B-fragment order, bf16.
// dest: frag (ks,f), lane, j  ->  Wp[((ks*8+f)*64+lane)*8 + j]
__global__ __launch_bounds__(256) void k_pack_w1(const float* __restrict__ Wl,
                                                 const float* __restrict__ Wr,
                                                 ushort* __restrict__ Wp) {
  int t = blockIdx.x * 256 + threadIdx.x;
  if (t >= 4096) return;
  int lane = t & 63, f = (t >> 6) & 7, ks = t >> 9;
  int col = f * 16 + (lane & 15);
  int k0 = ks * 32 + (lane >> 4) * 8;
#pragma unroll
  for (int j = 0; j < 8; ++j) {
    int k = k0 + j;
    float w = (k < 128) ? Wl[k * 128 + col] : Wr[(k - 128) * 128 + col];
    Wp[t * 8 + j] = f2bf(w);
  }
}

// pack [Wl2;Wr2] (256x40 f32) into 3 col-fragments (pad cols 40..47 with 0)
__global__ __launch_bounds__(256) void k_pack_w2(const float* __restrict__ Wl,
                                                 const float* __restrict__ Wr,
                                                 ushort* __restrict__ Wp) {
  int t = blockIdx.x * 256 + threadIdx.x;
  if (t >= 1536) return;
  int lane = t & 63, rem = t >> 6;
  int f = rem % 3, ks = rem / 3;
  int col = f * 16 + (lane & 15);
  int k0 = ks * 32 + (lane >> 4) * 8;
#pragma unroll
  for (int j = 0; j < 8; ++j) {
    int k = k0 + j;
    float w = 0.f;
    if (col < CLSN) w = (k < 128) ? Wl[k * CLSN + col] : Wr[(k - 128) * CLSN + col];
    Wp[t * 8 + j] = f2bf(w);
  }
}

// ---------------- CSR build ----------------
__global__ void k_deg(const int* __restrict__ dst, int* __restrict__ deg, int E) {
  int e = blockIdx.x * blockDim.x + threadIdx.x;
  if (e < E) atomicAdd(&deg[dst[e]], 1);
}

__global__ __launch_bounds__(256) void k_chunksum(const int* __restrict__ deg,
                                                  int* __restrict__ bsum, int n) {
  __shared__ int s[4];
  int blk = blockIdx.x, tid = threadIdx.x;
  int i0 = blk * 1024 + tid * 4;
  int t = 0;
#pragma unroll
  for (int j = 0; j < 4; ++j) t += (i0 + j < n) ? deg[i0 + j] : 0;
#pragma unroll
  for (int d = 32; d; d >>= 1) t += __shfl_down(t, d);
  if ((tid & 63) == 0) s[tid >> 6] = t;
  __syncthreads();
  if (tid == 0) bsum[blk] = s[0] + s[1] + s[2] + s[3];
}

__global__ __launch_bounds__(256) void k_scan_small(const int* __restrict__ bsum,
                                                    int* __restrict__ bbase, int nb) {
  __shared__ int s[256];
  int tid = threadIdx.x;
  int v = (tid < nb) ? bsum[tid] : 0;
  s[tid] = v;
  __syncthreads();
  for (int d = 1; d < 256; d <<= 1) {
    int u = (tid >= d) ? s[tid - d] : 0;
    __syncthreads();
    s[tid] += u;
    __syncthreads();
  }
  if (tid < nb) bbase[tid] = s[tid] - v;  // exclusive
}

__global__ __launch_bounds__(256) void k_scan_final(const int* __restrict__ deg,
                                                    const int* __restrict__ bbase,
                                                    int* __restrict__ offsets,
                                                    int* __restrict__ cursor, int n) {
  __shared__ int s_w[4];
  int blk = blockIdx.x, tid = threadIdx.x, lane = tid & 63, w = tid >> 6;
  int i0 = blk * 1024 + tid * 4;
  int v[4];
  int t = 0;
#pragma unroll
  for (int j = 0; j < 4; ++j) {
    v[j] = (i0 + j < n) ? deg[i0 + j] : 0;
    t += v[j];
  }
  int incl = t;
#pragma unroll
  for (int d = 1; d < 64; d <<= 1) {
    int u = __shfl_up(incl, d);
    if (lane >= d) incl += u;
  }
  if (lane == 63) s_w[w] = incl;
  __syncthreads();
  int wbase = 0;
  for (int q = 0; q < w; ++q) wbase += s_w[q];
  int run = bbase[blk] + wbase + (incl - t);
#pragma unroll
  for (int j = 0; j < 4; ++j) {
    if (i0 + j < n) {
      cursor[i0 + j] = run;
      offsets[i0 + j + 1] = run + v[j];
      run += v[j];
    }
  }
  if (blk == 0 && tid == 0) offsets[0] = 0;
}

__global__ void k_scatter(const int* __restrict__ src, const int* __restrict__ dst,
                          int* __restrict__ cursor, int* __restrict__ srcs, int E) {
  int e = blockIdx.x * blockDim.x + threadIdx.x;
  if (e < E) {
    int d = dst[e];
    int p = atomicAdd(&cursor[d], 1);
    srcs[p] = src[e];
  }
}

// ---------------- mean aggregation (bf16 in, bf16 out, fp32 accum) ----------------
__global__ __launch_bounds__(256) void k_aggregate(const ushort* __restrict__ feat,
                                                   const int* __restrict__ offsets,
                                                   const int* __restrict__ srcs,
                                                   ushort* __restrict__ mean, int n) {
  int gw = (blockIdx.x * 256 + threadIdx.x) >> 6;
  int lane = threadIdx.x & 63;
  if (gw >= n) return;
  const uint* fp = reinterpret_cast<const uint*>(feat);
  int beg = offsets[gw], end = offsets[gw + 1];
  float ax = 0.f, ay = 0.f;
  for (int chunk = beg; chunk < end; chunk += 64) {
    int cnt = min(64, end - chunk);
    int s = (lane < cnt) ? srcs[chunk + lane] : 0;
    int k = 0;
    for (; k + 3 < cnt; k += 4) {
      int s0 = __shfl(s, k), s1 = __shfl(s, k + 1);
      int s2 = __shfl(s, k + 2), s3 = __shfl(s, k + 3);
      uint u0 = fp[(size_t)s0 * 64 + lane];
      uint u1 = fp[(size_t)s1 * 64 + lane];
      uint u2 = fp[(size_t)s2 * 64 + lane];
      uint u3 = fp[(size_t)s3 * 64 + lane];
      ax += __uint_as_float(u0 << 16) + __uint_as_float(u1 << 16) +
            __uint_as_float(u2 << 16) + __uint_as_float(u3 << 16);
      ay += __uint_as_float(u0 & 0xFFFF0000u) + __uint_as_float(u1 & 0xFFFF0000u) +
            __uint_as_float(u2 & 0xFFFF0000u) + __uint_as_float(u3 & 0xFFFF0000u);
    }
    for (; k < cnt; ++k) {
      int s0 = __shfl(s, k);
      uint u0 = fp[(size_t)s0 * 64 + lane];
      ax += __uint_as_float(u0 << 16);
      ay += __uint_as_float(u0 & 0xFFFF0000u);
    }
  }
  int dg = end - beg;
  float inv = dg > 0 ? 1.f / (float)dg : 0.f;
  uint lo = f2bf(ax * inv), hi = f2bf(ay * inv);
  reinterpret_cast<uint*>(mean)[(size_t)gw * 64 + lane] = lo | (hi << 16);
}

// ---------------- layer1 MFMA GEMM: h = relu([mean|x]@Wp1 + b1), bf16 out ------------
__global__ __launch_bounds__(256) void k_mfma1(const ushort* __restrict__ meanb,
                                               const ushort* __restrict__ rootb,
                                               const ushort* __restrict__ Wp,
                                               const float* __restrict__ b,
                                               ushort* __restrict__ h, int nrows) {
  __shared__ __align__(16) ushort As[64 * 256];  // 32KB, XOR-swizzled
  const int tid = threadIdx.x;
  const int row0 = blockIdx.x * 64;
#pragma unroll
  for (int i = 0; i < 8; ++i) {
    int c = tid + i * 256;  // 2048 16B-chunks
    int r = c >> 5;
    int c16 = c & 31;
    int grow = row0 + r;
    short8v v = {0, 0, 0, 0, 0, 0, 0, 0};
    if (grow < nrows) {
      const ushort* srcp = (c16 < 16) ? (meanb + (size_t)grow * 128 + c16 * 8)
                                      : (rootb + (size_t)grow * 128 + (c16 - 16) * 8);
      v = *reinterpret_cast<const short8v*>(srcp);
    }
    int dbyte = r * 512 + ((c16 * 16) ^ ((r & 7) << 4));
    *reinterpret_cast<short8v*>(reinterpret_cast<char*>(As) + dbyte) = v;
  }
  __syncthreads();
  const int lane = tid & 63;
  const int rbase = (tid >> 6) * 16;
  const int arow = rbase + (lane & 15);
  const int axor = (arow & 7) << 4;
  const short8v* Wp8 = reinterpret_cast<const short8v*>(Wp);
  float4v acc[8];
#pragma unroll
  for (int f = 0; f < 8; ++f) acc[f] = {0.f, 0.f, 0.f, 0.f};
#pragma unroll
  for (int ks = 0; ks < 8; ++ks) {
    int abyte = arow * 512 + ((ks * 64 + (lane >> 4) * 16) ^ axor);
    short8v a = *reinterpret_cast<const short8v*>(reinterpret_cast<const char*>(As) + abyte);
#pragma unroll
    for (int f = 0; f < 8; ++f) {
      short8v bf = Wp8[(ks * 8 + f) * 64 + lane];
      acc[f] = __builtin_amdgcn_mfma_f32_16x16x32_bf16(a, bf, acc[f], 0, 0, 0);
    }
  }
  const int col_lo = lane & 15;
  const int rq = (lane >> 4) * 4;
#pragma unroll
  for (int f = 0; f < 8; ++f) {
    int col = f * 16 + col_lo;
    float bias = b[col];
#pragma unroll
    for (int r = 0; r < 4; ++r) {
      int row = row0 + rbase + rq + r;
      if (row < nrows) {
        float vv = fmaxf(acc[f][r] + bias, 0.f);
        h[(size_t)row * 128 + col] = f2bf(vv);
      }
    }
  }
}

// ---------------- layer2 MFMA GEMM: out = [mean2|h]@Wp2 + b2, fp32 out ----------------
__global__ __launch_bounds__(256) void k_mfma2(const ushort* __restrict__ meanb,
                                               const ushort* __restrict__ rootb,
                                               const ushort* __restrict__ Wp,
                                               const float* __restrict__ b,
                                               float* __restrict__ out, int nrows) {
  __shared__ __align__(16) ushort As[64 * 256];
  const int tid = threadIdx.x;
  const int row0 = blockIdx.x * 64;
#pragma unroll
  for (int i = 0; i < 8; ++i) {
    int c = tid + i * 256;
    int r = c >> 5;
    int c16 = c & 31;
    int grow = row0 + r;
    short8v v = {0, 0, 0, 0, 0, 0, 0, 0};
    if (grow < nrows) {
      const ushort* srcp = (c16 < 16) ? (meanb + (size_t)grow * 128 + c16 * 8)
                                      : (rootb + (size_t)grow * 128 + (c16 - 16) * 8);
      v = *reinterpret_cast<const short8v*>(srcp);
    }
    int dbyte = r * 512 + ((c16 * 16) ^ ((r & 7) << 4));
    *reinterpret_cast<short8v*>(reinterpret_cast<char*>(As) + dbyte) = v;
  }
  __syncthreads();
  const int lane = tid & 63;
  const int rbase = (tid >> 6) * 16;
  const int arow = rbase + (lane & 15);
  const int axor = (arow & 7) << 4;
  const short8v* Wp8 = reinterpret_cast<const short8v*>(Wp);
  float4v acc[3];
#pragma unroll
  for (int f = 0; f < 3; ++f) acc[f] = {0.f, 0.f, 0.f, 0.f};
#pragma unroll
  for (int ks = 0; ks < 8; ++ks) {
    int abyte = arow * 512 + ((ks * 64 + (lane >> 4) * 16) ^ axor);
    short8v a = *reinterpret_cast<const short8v*>(reinterpret_cast<const char*>(As) + abyte);
#pragma unroll
    for (int f = 0; f < 3; ++f) {
      short8v bf = Wp8[(ks * 3 + f) * 64 + lane];
      acc[f] = __builtin_amdgcn_mfma_f32_16x16x32_bf16(a, bf, acc[f], 0, 0, 0);
    }
  }
  const int col_lo = lane & 15;
  const int rq = (lane >> 4) * 4;
#pragma unroll
  for (int f = 0; f < 3; ++f) {
    int col = f * 16 + col_lo;
    if (col < CLSN) {
      float bias = b[col];
#pragma unroll
      for (int r = 0; r < 4; ++r) {
        int row = row0 + rbase + rq + r;
        if (row < nrows) out[(size_t)row * CLSN + col] = acc[f][r] + bias;
      }
    }
  }
}

extern "C" void kernel_launch(void* const* d_in, const int* in_sizes, int n_in,
                              void* d_out, int out_size, void* d_ws, size_t ws_size,
                              hipStream_t stream) {
  const float* x = (const float*)d_in[0];
  const int* ei = (const int*)d_in[1];
  const float* Wl1 = (const float*)d_in[2];
  const float* Wr1 = (const float*)d_in[3];
  const float* b1 = (const float*)d_in[4];
  const float* Wl2 = (const float*)d_in[5];
  const float* Wr2 = (const float*)d_in[6];
  const float* b2 = (const float*)d_in[7];
  float* out = (float*)d_out;

  const int n = in_sizes[0] / F;
  const int E = in_sizes[1] / 2;
  const int* src = ei;
  const int* dst = ei + E;

  size_t off = 0;
  auto alloc = [&](size_t bytes) {
    size_t cur = off;
    off = (off + bytes + 255) & ~(size_t)255;
    return cur;
  };
  char* w = (char*)d_ws;
  int* deg = (int*)(w + alloc((size_t)n * 4));
  int* offsets = (int*)(w + alloc((size_t)(n + 1) * 4));
  int* cursor = (int*)(w + alloc((size_t)n * 4));
  int* srcs = (int*)(w + alloc((size_t)E * 4));
  int* bsum = (int*)(w + alloc(256 * 4));
  int* bbase = (int*)(w + alloc(256 * 4));
  ushort* xb = (ushort*)(w + alloc((size_t)n * F * 2));
  ushort* hb = (ushort*)(w + alloc((size_t)n * F * 2));
  ushort* meanb = (ushort*)(w + alloc((size_t)n * F * 2));
  ushort* Wp1 = (ushort*)(w + alloc(32768 * 2));
  ushort* Wp2 = (ushort*)(w + alloc(12288 * 2));
  (void)ws_size;

  const int nb = (n + 1023) / 1024;

  // casts / weight packing
  k_cast<<<(n * 32 + 255) / 256, 256, 0, stream>>>(x, xb, n * 32);
  k_pack_w1<<<16, 256, 0, stream>>>(Wl1, Wr1, Wp1);
  k_pack_w2<<<6, 256, 0, stream>>>(Wl2, Wr2, Wp2);

  // CSR build
  hipMemsetAsync(deg, 0, (size_t)n * 4, stream);
  k_deg<<<(E + 255) / 256, 256, 0, stream>>>(dst, deg, E);
  k_chunksum<<<nb, 256, 0, stream>>>(deg, bsum, n);
  k_scan_small<<<1, 256, 0, stream>>>(bsum, bbase, nb);
  k_scan_final<<<nb, 256, 0, stream>>>(deg, bbase, offsets, cursor, n);
  k_scatter<<<(E + 255) / 256, 256, 0, stream>>>(src, dst, cursor, srcs, E);

  // layer 1
  k_aggregate<<<(n * 64 + 255) / 256, 256, 0, stream>>>(xb, offsets, srcs, meanb, n);
  k_mfma1<<<(n + 63) / 64, 256, 0, stream>>>(meanb, xb, Wp1, b1, hb, n);

  // layer 2
  k_aggregate<<<(n * 64 + 255) / 256, 256, 0, stream>>>(hb, offsets, srcs, meanb, n);
  k_mfma2<<<(n + 63) / 64, 256, 0, stream>>>(meanb, hb, Wp2, b2, out, n);
}

// Round 3
// 335.642 us; speedup vs baseline: 2.1850x; 1.1352x over previous
//
#include <hip/hip_runtime.h>

#define F 128
#define CLSN 40

typedef __attribute__((ext_vector_type(8))) short short8v;
typedef __attribute__((ext_vector_type(4))) float float4v;

static __device__ inline ushort f2bf(float f) {
  uint u = __float_as_uint(f);
  uint r = (u + 0x7FFFu + ((u >> 16) & 1u)) >> 16;
  return (ushort)r;
}

// ---------------- casts / packing ----------------
__global__ __launch_bounds__(256) void k_cast(const float* __restrict__ in,
                                              ushort* __restrict__ outb, int nelem4) {
  int i = blockIdx.x * 256 + threadIdx.x;
  if (i < nelem4) {
    float4 v = reinterpret_cast<const float4*>(in)[i];
    ushort4 o;
    o.x = f2bf(v.x); o.y = f2bf(v.y); o.z = f2bf(v.z); o.w = f2bf(v.w);
    reinterpret_cast<ushort4*>(outb)[i] = o;
  }
}

// pack [Wl;Wr] (256x128 f32) into MFMA B-fragment order, bf16.
__global__ __launch_bounds__(256) void k_pack_w1(const float* __restrict__ Wl,
                                                 const float* __restrict__ Wr,
                                                 ushort* __restrict__ Wp) {
  int t = blockIdx.x * 256 + threadIdx.x;
  if (t >= 4096) return;
  int lane = t & 63, f = (t >> 6) & 7, ks = t >> 9;
  int col = f * 16 + (lane & 15);
  int k0 = ks * 32 + (lane >> 4) * 8;
#pragma unroll
  for (int j = 0; j < 8; ++j) {
    int k = k0 + j;
    float w = (k < 128) ? Wl[k * 128 + col] : Wr[(k - 128) * 128 + col];
    Wp[t * 8 + j] = f2bf(w);
  }
}

__global__ __launch_bounds__(256) void k_pack_w2(const float* __restrict__ Wl,
                                                 const float* __restrict__ Wr,
                                                 ushort* __restrict__ Wp) {
  int t = blockIdx.x * 256 + threadIdx.x;
  if (t >= 1536) return;
  int lane = t & 63, rem = t >> 6;
  int f = rem % 3, ks = rem / 3;
  int col = f * 16 + (lane & 15);
  int k0 = ks * 32 + (lane >> 4) * 8;
#pragma unroll
  for (int j = 0; j < 8; ++j) {
    int k = k0 + j;
    float w = 0.f;
    if (col < CLSN) w = (k < 128) ? Wl[k * CLSN + col] : Wr[(k - 128) * CLSN + col];
    Wp[t * 8 + j] = f2bf(w);
  }
}

// ---------------- CSR build ----------------
__global__ void k_deg(const int* __restrict__ dst, int* __restrict__ deg, int E) {
  int e = blockIdx.x * blockDim.x + threadIdx.x;
  if (e < E) atomicAdd(&deg[dst[e]], 1);
}

__global__ __launch_bounds__(256) void k_chunksum(const int* __restrict__ deg,
                                                  int* __restrict__ bsum, int n) {
  __shared__ int s[4];
  int blk = blockIdx.x, tid = threadIdx.x;
  int i0 = blk * 1024 + tid * 4;
  int t = 0;
#pragma unroll
  for (int j = 0; j < 4; ++j) t += (i0 + j < n) ? deg[i0 + j] : 0;
#pragma unroll
  for (int d = 32; d; d >>= 1) t += __shfl_down(t, d);
  if ((tid & 63) == 0) s[tid >> 6] = t;
  __syncthreads();
  if (tid == 0) bsum[blk] = s[0] + s[1] + s[2] + s[3];
}

__global__ __launch_bounds__(256) void k_scan_small(const int* __restrict__ bsum,
                                                    int* __restrict__ bbase, int nb) {
  __shared__ int s[256];
  int tid = threadIdx.x;
  int v = (tid < nb) ? bsum[tid] : 0;
  s[tid] = v;
  __syncthreads();
  for (int d = 1; d < 256; d <<= 1) {
    int u = (tid >= d) ? s[tid - d] : 0;
    __syncthreads();
    s[tid] += u;
    __syncthreads();
  }
  if (tid < nb) bbase[tid] = s[tid] - v;  // exclusive
}

__global__ __launch_bounds__(256) void k_scan_final(const int* __restrict__ deg,
                                                    const int* __restrict__ bbase,
                                                    int* __restrict__ offsets,
                                                    int* __restrict__ cursor, int n) {
  __shared__ int s_w[4];
  int blk = blockIdx.x, tid = threadIdx.x, lane = tid & 63, w = tid >> 6;
  int i0 = blk * 1024 + tid * 4;
  int v[4];
  int t = 0;
#pragma unroll
  for (int j = 0; j < 4; ++j) {
    v[j] = (i0 + j < n) ? deg[i0 + j] : 0;
    t += v[j];
  }
  int incl = t;
#pragma unroll
  for (int d = 1; d < 64; d <<= 1) {
    int u = __shfl_up(incl, d);
    if (lane >= d) incl += u;
  }
  if (lane == 63) s_w[w] = incl;
  __syncthreads();
  int wbase = 0;
  for (int q = 0; q < w; ++q) wbase += s_w[q];
  int run = bbase[blk] + wbase + (incl - t);
#pragma unroll
  for (int j = 0; j < 4; ++j) {
    if (i0 + j < n) {
      cursor[i0 + j] = run;
      offsets[i0 + j + 1] = run + v[j];
      run += v[j];
    }
  }
  if (blk == 0 && tid == 0) offsets[0] = 0;
}

// XCD-class-partitioned scatter: class c = blockIdx.x & 7 handles edges whose
// dst granule (dst>>8) % 8 == c. Writes to srcs land in ~16KB contiguous windows
// per granule -> 64B lines filled by a single XCD class -> ~1x write amplification.
__global__ __launch_bounds__(256) void k_scatter_part(const int* __restrict__ src,
                                                      const int* __restrict__ dst,
                                                      int* __restrict__ cursor,
                                                      int* __restrict__ srcs, int E) {
  const int c = blockIdx.x & 7;
  const int nb = gridDim.x >> 3;
  const int wb = blockIdx.x >> 3;
  const int nchunk = E >> 2;
  const int stride = nb * 256;
  for (int i = wb * 256 + threadIdx.x; i < nchunk; i += stride) {
    int4 d4 = reinterpret_cast<const int4*>(dst)[i];
    int4 s4 = reinterpret_cast<const int4*>(src)[i];
    if (((d4.x >> 8) & 7) == c) srcs[atomicAdd(&cursor[d4.x], 1)] = s4.x;
    if (((d4.y >> 8) & 7) == c) srcs[atomicAdd(&cursor[d4.y], 1)] = s4.y;
    if (((d4.z >> 8) & 7) == c) srcs[atomicAdd(&cursor[d4.z], 1)] = s4.z;
    if (((d4.w >> 8) & 7) == c) srcs[atomicAdd(&cursor[d4.w], 1)] = s4.w;
  }
  if (wb == 0) {
    for (int e = (E & ~3) + threadIdx.x; e < E; e += 256) {
      int d = dst[e];
      if (((d >> 8) & 7) == c) srcs[atomicAdd(&cursor[d], 1)] = src[e];
    }
  }
}

// ---------------- mean aggregation (bf16 in, bf16 out, fp32 accum) ----------------
__global__ __launch_bounds__(256) void k_aggregate(const ushort* __restrict__ feat,
                                                   const int* __restrict__ offsets,
                                                   const int* __restrict__ srcs,
                                                   ushort* __restrict__ mean, int n) {
  int gw = (blockIdx.x * 256 + threadIdx.x) >> 6;
  int lane = threadIdx.x & 63;
  if (gw >= n) return;
  const uint* fp = reinterpret_cast<const uint*>(feat);
  int beg = offsets[gw], end = offsets[gw + 1];
  float ax = 0.f, ay = 0.f;
  for (int chunk = beg; chunk < end; chunk += 64) {
    int cnt = min(64, end - chunk);
    int s = (lane < cnt) ? srcs[chunk + lane] : 0;
    int k = 0;
    for (; k + 7 < cnt; k += 8) {
      int s0 = __shfl(s, k), s1 = __shfl(s, k + 1);
      int s2 = __shfl(s, k + 2), s3 = __shfl(s, k + 3);
      int s4 = __shfl(s, k + 4), s5 = __shfl(s, k + 5);
      int s6 = __shfl(s, k + 6), s7 = __shfl(s, k + 7);
      uint u0 = fp[(size_t)s0 * 64 + lane];
      uint u1 = fp[(size_t)s1 * 64 + lane];
      uint u2 = fp[(size_t)s2 * 64 + lane];
      uint u3 = fp[(size_t)s3 * 64 + lane];
      uint u4 = fp[(size_t)s4 * 64 + lane];
      uint u5 = fp[(size_t)s5 * 64 + lane];
      uint u6 = fp[(size_t)s6 * 64 + lane];
      uint u7 = fp[(size_t)s7 * 64 + lane];
      ax += __uint_as_float(u0 << 16) + __uint_as_float(u1 << 16) +
            __uint_as_float(u2 << 16) + __uint_as_float(u3 << 16) +
            __uint_as_float(u4 << 16) + __uint_as_float(u5 << 16) +
            __uint_as_float(u6 << 16) + __uint_as_float(u7 << 16);
      ay += __uint_as_float(u0 & 0xFFFF0000u) + __uint_as_float(u1 & 0xFFFF0000u) +
            __uint_as_float(u2 & 0xFFFF0000u) + __uint_as_float(u3 & 0xFFFF0000u) +
            __uint_as_float(u4 & 0xFFFF0000u) + __uint_as_float(u5 & 0xFFFF0000u) +
            __uint_as_float(u6 & 0xFFFF0000u) + __uint_as_float(u7 & 0xFFFF0000u);
    }
    for (; k < cnt; ++k) {
      int s0 = __shfl(s, k);
      uint u0 = fp[(size_t)s0 * 64 + lane];
      ax += __uint_as_float(u0 << 16);
      ay += __uint_as_float(u0 & 0xFFFF0000u);
    }
  }
  int dg = end - beg;
  float inv = dg > 0 ? 1.f / (float)dg : 0.f;
  uint lo = f2bf(ax * inv), hi = f2bf(ay * inv);
  reinterpret_cast<uint*>(mean)[(size_t)gw * 64 + lane] = lo | (hi << 16);
}

// ---------------- layer1 MFMA GEMM: h = relu([mean|x]@Wp1 + b1), bf16 out ------------
__global__ __launch_bounds__(256) void k_mfma1(const ushort* __restrict__ meanb,
                                               const ushort* __restrict__ rootb,
                                               const ushort* __restrict__ Wp,
                                               const float* __restrict__ b,
                                               ushort* __restrict__ h, int nrows) {
  __shared__ __align__(16) ushort As[64 * 256];  // 32KB, XOR-swizzled
  const int tid = threadIdx.x;
  const int row0 = blockIdx.x * 64;
#pragma unroll
  for (int i = 0; i < 8; ++i) {
    int c = tid + i * 256;
    int r = c >> 5;
    int c16 = c & 31;
    int grow = row0 + r;
    short8v v = {0, 0, 0, 0, 0, 0, 0, 0};
    if (grow < nrows) {
      const ushort* srcp = (c16 < 16) ? (meanb + (size_t)grow * 128 + c16 * 8)
                                      : (rootb + (size_t)grow * 128 + (c16 - 16) * 8);
      v = *reinterpret_cast<const short8v*>(srcp);
    }
    int dbyte = r * 512 + ((c16 * 16) ^ ((r & 7) << 4));
    *reinterpret_cast<short8v*>(reinterpret_cast<char*>(As) + dbyte) = v;
  }
  __syncthreads();
  const int lane = tid & 63;
  const int rbase = (tid >> 6) * 16;
  const int arow = rbase + (lane & 15);
  const int axor = (arow & 7) << 4;
  const short8v* Wp8 = reinterpret_cast<const short8v*>(Wp);
  float4v acc[8];
#pragma unroll
  for (int f = 0; f < 8; ++f) acc[f] = {0.f, 0.f, 0.f, 0.f};
#pragma unroll
  for (int ks = 0; ks < 8; ++ks) {
    int abyte = arow * 512 + ((ks * 64 + (lane >> 4) * 16) ^ axor);
    short8v a = *reinterpret_cast<const short8v*>(reinterpret_cast<const char*>(As) + abyte);
#pragma unroll
    for (int f = 0; f < 8; ++f) {
      short8v bf = Wp8[(ks * 8 + f) * 64 + lane];
      acc[f] = __builtin_amdgcn_mfma_f32_16x16x32_bf16(a, bf, acc[f], 0, 0, 0);
    }
  }
  const int col_lo = lane & 15;
  const int rq = (lane >> 4) * 4;
#pragma unroll
  for (int f = 0; f < 8; ++f) {
    int col = f * 16 + col_lo;
    float bias = b[col];
#pragma unroll
    for (int r = 0; r < 4; ++r) {
      int row = row0 + rbase + rq + r;
      if (row < nrows) {
        float vv = fmaxf(acc[f][r] + bias, 0.f);
        h[(size_t)row * 128 + col] = f2bf(vv);
      }
    }
  }
}

// ---------------- layer2 MFMA GEMM: out = [mean2|h]@Wp2 + b2, fp32 out ----------------
__global__ __launch_bounds__(256) void k_mfma2(const ushort* __restrict__ meanb,
                                               const ushort* __restrict__ rootb,
                                               const ushort* __restrict__ Wp,
                                               const float* __restrict__ b,
                                               float* __restrict__ out, int nrows) {
  __shared__ __align__(16) ushort As[64 * 256];
  const int tid = threadIdx.x;
  const int row0 = blockIdx.x * 64;
#pragma unroll
  for (int i = 0; i < 8; ++i) {
    int c = tid + i * 256;
    int r = c >> 5;
    int c16 = c & 31;
    int grow = row0 + r;
    short8v v = {0, 0, 0, 0, 0, 0, 0, 0};
    if (grow < nrows) {
      const ushort* srcp = (c16 < 16) ? (meanb + (size_t)grow * 128 + c16 * 8)
                                      : (rootb + (size_t)grow * 128 + (c16 - 16) * 8);
      v = *reinterpret_cast<const short8v*>(srcp);
    }
    int dbyte = r * 512 + ((c16 * 16) ^ ((r & 7) << 4));
    *reinterpret_cast<short8v*>(reinterpret_cast<char*>(As) + dbyte) = v;
  }
  __syncthreads();
  const int lane = tid & 63;
  const int rbase = (tid >> 6) * 16;
  const int arow = rbase + (lane & 15);
  const int axor = (arow & 7) << 4;
  const short8v* Wp8 = reinterpret_cast<const short8v*>(Wp);
  float4v acc[3];
#pragma unroll
  for (int f = 0; f < 3; ++f) acc[f] = {0.f, 0.f, 0.f, 0.f};
#pragma unroll
  for (int ks = 0; ks < 8; ++ks) {
    int abyte = arow * 512 + ((ks * 64 + (lane >> 4) * 16) ^ axor);
    short8v a = *reinterpret_cast<const short8v*>(reinterpret_cast<const char*>(As) + abyte);
#pragma unroll
    for (int f = 0; f < 3; ++f) {
      short8v bf = Wp8[(ks * 3 + f) * 64 + lane];
      acc[f] = __builtin_amdgcn_mfma_f32_16x16x32_bf16(a, bf, acc[f], 0, 0, 0);
    }
  }
  const int col_lo = lane & 15;
  const int rq = (lane >> 4) * 4;
#pragma unroll
  for (int f = 0; f < 3; ++f) {
    int col = f * 16 + col_lo;
    if (col < CLSN) {
      float bias = b[col];
#pragma unroll
      for (int r = 0; r < 4; ++r) {
        int row = row0 + rbase + rq + r;
        if (row < nrows) out[(size_t)row * CLSN + col] = acc[f][r] + bias;
      }
    }
  }
}

extern "C" void kernel_launch(void* const* d_in, const int* in_sizes, int n_in,
                              void* d_out, int out_size, void* d_ws, size_t ws_size,
                              hipStream_t stream) {
  const float* x = (const float*)d_in[0];
  const int* ei = (const int*)d_in[1];
  const float* Wl1 = (const float*)d_in[2];
  const float* Wr1 = (const float*)d_in[3];
  const float* b1 = (const float*)d_in[4];
  const float* Wl2 = (const float*)d_in[5];
  const float* Wr2 = (const float*)d_in[6];
  const float* b2 = (const float*)d_in[7];
  float* out = (float*)d_out;

  const int n = in_sizes[0] / F;
  const int E = in_sizes[1] / 2;
  const int* src = ei;
  const int* dst = ei + E;

  size_t off = 0;
  auto alloc = [&](size_t bytes) {
    size_t cur = off;
    off = (off + bytes + 255) & ~(size_t)255;
    return cur;
  };
  char* w = (char*)d_ws;
  int* deg = (int*)(w + alloc((size_t)n * 4));
  int* offsets = (int*)(w + alloc((size_t)(n + 1) * 4));
  int* cursor = (int*)(w + alloc((size_t)n * 4));
  int* srcs = (int*)(w + alloc((size_t)E * 4));
  int* bsum = (int*)(w + alloc(256 * 4));
  int* bbase = (int*)(w + alloc(256 * 4));
  ushort* xb = (ushort*)(w + alloc((size_t)n * F * 2));
  ushort* hb = (ushort*)(w + alloc((size_t)n * F * 2));
  ushort* meanb = (ushort*)(w + alloc((size_t)n * F * 2));
  ushort* Wp1 = (ushort*)(w + alloc(32768 * 2));
  ushort* Wp2 = (ushort*)(w + alloc(12288 * 2));
  (void)ws_size;

  const int nb = (n + 1023) / 1024;

  // casts / weight packing
  k_cast<<<(n * 32 + 255) / 256, 256, 0, stream>>>(x, xb, n * 32);
  k_pack_w1<<<16, 256, 0, stream>>>(Wl1, Wr1, Wp1);
  k_pack_w2<<<6, 256, 0, stream>>>(Wl2, Wr2, Wp2);

  // CSR build
  hipMemsetAsync(deg, 0, (size_t)n * 4, stream);
  k_deg<<<(E + 255) / 256, 256, 0, stream>>>(dst, deg, E);
  k_chunksum<<<nb, 256, 0, stream>>>(deg, bsum, n);
  k_scan_small<<<1, 256, 0, stream>>>(bsum, bbase, nb);
  k_scan_final<<<nb, 256, 0, stream>>>(deg, bbase, offsets, cursor, n);
  k_scatter_part<<<1024, 256, 0, stream>>>(src, dst, cursor, srcs, E);

  // layer 1
  k_aggregate<<<(n * 64 + 255) / 256, 256, 0, stream>>>(xb, offsets, srcs, meanb, n);
  k_mfma1<<<(n + 63) / 64, 256, 0, stream>>>(meanb, xb, Wp1, b1, hb, n);

  // layer 2
  k_aggregate<<<(n * 64 + 255) / 256, 256, 0, stream>>>(hb, offsets, srcs, meanb, n);
  k_mfma2<<<(n + 63) / 64, 256, 0, stream>>>(meanb, hb, Wp2, b2, out, n);
}